// Round 1
// 74.978 us; speedup vs baseline: 1.0106x; 1.0106x over previous
//
#include <hip/hip_runtime.h>

// ProposalLayer: for each proposal (b,p), find nearest GT among the first
// num_person[b] GT slots, emit [xyz, proposal2gt, conf, bbox(2)] -> [B,P,7].
//
// V2: the G-loop was LDS-latency-serialized (3 scalar ds_read_b32 per GT,
// one exposed ~120cy latency per iteration). Now GT points are staged as
// padded float4 (one ds_read_b128 per GT) and the loop is hand-unrolled x4
// so 4 independent 16B loads are in flight per group, followed by a pure
// VALU block. Global input loads are hoisted above __syncthreads so their
// HBM latency hides under GT staging + the barrier.

#define BB 256
#define PP 1024
#define GG 128

__global__ __launch_bounds__(256) void proposal_layer_kernel(
    const float* __restrict__ topk_index,   // [B,P,3]
    const float* __restrict__ topk_confs,   // [B,P]
    const float* __restrict__ bbox_preds,   // [B,P,2]
    const float* __restrict__ gt_3d,        // [B,G,3]
    const float* __restrict__ gt_bbox,      // [B,G,2]
    const int*   __restrict__ num_person,   // [B]
    float* __restrict__ out)                // [B,P,7]
{
    __shared__ float4 s_gt[GG];      // 2048 B, xyz padded to 16 B
    __shared__ float  s_bb[GG * 2];  // 1024 B

    const int blocks_per_b = PP / 256;          // 4
    const int b     = blockIdx.x / blocks_per_b;
    const int ptile = blockIdx.x % blocks_per_b;
    const int t     = threadIdx.x;
    const int p     = ptile * 256 + t;

    const size_t bp = (size_t)b * PP + p;

    // Issue ALL global input loads before the barrier: their latency
    // overlaps the GT staging + __syncthreads.
    const float x    = topk_index[bp * 3 + 0];
    const float y    = topk_index[bp * 3 + 1];
    const float z    = topk_index[bp * 3 + 2];
    const float conf = topk_confs[bp];
    const float bp0  = bbox_preds[bp * 2 + 0];
    const float bp1  = bbox_preds[bp * 2 + 1];
    const int np_b   = num_person[b];           // scalar broadcast

    // Stage GT data for this batch into LDS.
    if (t < GG) {
        const float* g3 = gt_3d + (size_t)b * (GG * 3) + (size_t)t * 3;
        s_gt[t] = make_float4(g3[0], g3[1], g3[2], 0.0f);
    }
    s_bb[t] = gt_bbox[(size_t)b * (GG * 2) + t];  // 256 floats exactly
    __syncthreads();

    // argmin over squared distance; strict < keeps first-occurrence
    // semantics (sequential compares, also within each unrolled group).
    float best = 3.402823466e+38f;
    int   bidx = 0;

    int g = 0;
    for (; g + 4 <= np_b; g += 4) {
        const float4 q0 = s_gt[g + 0];
        const float4 q1 = s_gt[g + 1];
        const float4 q2 = s_gt[g + 2];
        const float4 q3 = s_gt[g + 3];

        float dx0 = x - q0.x, dy0 = y - q0.y, dz0 = z - q0.z;
        float dx1 = x - q1.x, dy1 = y - q1.y, dz1 = z - q1.z;
        float dx2 = x - q2.x, dy2 = y - q2.y, dz2 = z - q2.z;
        float dx3 = x - q3.x, dy3 = y - q3.y, dz3 = z - q3.z;
        const float d0 = dx0 * dx0 + dy0 * dy0 + dz0 * dz0;
        const float d1 = dx1 * dx1 + dy1 * dy1 + dz1 * dz1;
        const float d2 = dx2 * dx2 + dy2 * dy2 + dz2 * dz2;
        const float d3 = dx3 * dx3 + dy3 * dy3 + dz3 * dz3;

        if (d0 < best) { best = d0; bidx = g + 0; }
        if (d1 < best) { best = d1; bidx = g + 1; }
        if (d2 < best) { best = d2; bidx = g + 2; }
        if (d3 < best) { best = d3; bidx = g + 3; }
    }
    for (; g < np_b; ++g) {             // tail: at most 3 iterations
        const float4 q = s_gt[g];
        const float dx = x - q.x, dy = y - q.y, dz = z - q.z;
        const float d  = dx * dx + dy * dy + dz * dz;
        if (d < best) { best = d; bidx = g; }
    }

    // sqrt(best) > 500  <=>  best > 500^2 (both non-negative)
    const float p2g = (best > 500.0f * 500.0f) ? -1.0f : (float)bidx;

    // matched bbox gathered with min_gt unconditionally (matches reference)
    const float mb0 = s_bb[bidx * 2 + 0];
    const float mb1 = s_bb[bidx * 2 + 1];
    const bool cond = (p2g >= 0.0f) &&
                      ((bp0 < mb0 - 0.1f) || (bp1 < mb1 - 0.1f));
    const float o5 = cond ? mb0 : bp0;
    const float o6 = cond ? mb1 : bp1;

    float* o = out + bp * 7;
    o[0] = x;
    o[1] = y;
    o[2] = z;
    o[3] = p2g;
    o[4] = conf;
    o[5] = o5;
    o[6] = o6;
}

extern "C" void kernel_launch(void* const* d_in, const int* in_sizes, int n_in,
                              void* d_out, int out_size, void* d_ws, size_t ws_size,
                              hipStream_t stream) {
    const float* topk_index       = (const float*)d_in[0];
    const float* topk_confs       = (const float*)d_in[1];
    const float* match_bbox_preds = (const float*)d_in[2];
    const float* gt_3d            = (const float*)d_in[3];
    const float* gt_bbox          = (const float*)d_in[4];
    const int*   num_person       = (const int*)d_in[5];
    float* out = (float*)d_out;

    const int grid = BB * (PP / 256);   // 1024 blocks
    proposal_layer_kernel<<<grid, 256, 0, stream>>>(
        topk_index, topk_confs, match_bbox_preds, gt_3d, gt_bbox,
        num_person, out);
}